// Round 5
// baseline (172.045 us; speedup 1.0000x reference)
//
#include <hip/hip_runtime.h>
#include <hip/hip_fp16.h>

#define FH 200
#define FW 200
#define FHW 40000
#define FC 256
#define NBIN 49        // 7*7 output bins
#define NSAMP 196      // NBIN * 4 subsamples
#define OHS 66         // out_h [bin][ch] stride in halves = 33 dwords (odd ->
                       // full-period bank walk, <=2-way conflicts = free)

// Native clang vector for nontemporal builtins (HIP_vector_type is rejected).
typedef float  nfloat4 __attribute__((ext_vector_type(4)));

// ---------------------------------------------------------------------------
// Per-sample geometry: weights (pre-multiplied by valid-mask and 0.25 mean
// factor) and 4 bilinear-corner offsets (elements of the chosen layout).
// Matches the JAX reference (aligned coords, clamp-at-edge, valid in [-1,H]).
// __cosf/__sinf: hardware v_cos/v_sin, ~1e-5 rel err, irrelevant vs fp16 math.
// ---------------------------------------------------------------------------
__device__ __forceinline__ void compute_sample(const float* __restrict__ roi,
                                               int s, bool nhwc,
                                               float4* wout, int4* oout)
{
    int   b  = (int)roi[0];
    float cw = roi[1] * 0.25f - 0.5f;
    float ch = roi[2] * 0.25f - 0.5f;
    float rw = fmaxf(roi[3] * 0.25f, 1.0f);
    float rh = fmaxf(roi[4] * 0.25f, 1.0f);
    float th = roi[5] * 0.017453292519943295f;   // pi/180
    float ct = __cosf(th);
    float st = __sinf(th);
    float bin_h = rh / 7.0f;
    float bin_w = rw / 7.0f;

    int bin = s >> 2;
    int sub = s & 3;
    int iy  = sub >> 1;
    int ix  = sub & 1;
    int ph  = bin / 7;
    int pw  = bin - ph * 7;

    float fy = 0.25f + 0.5f * (float)iy;  // frac = {0.25, 0.75}
    float fx = 0.25f + 0.5f * (float)ix;
    float yy = -rh * 0.5f + ((float)ph + fy) * bin_h;
    float xx = -rw * 0.5f + ((float)pw + fx) * bin_w;
    float y  = yy * ct - xx * st + ch;
    float x  = yy * st + xx * ct + cw;

    bool valid = (y >= -1.0f) && (y <= (float)FH) && (x >= -1.0f) && (x <= (float)FW);
    y = fmaxf(y, 0.0f);
    x = fmaxf(x, 0.0f);
    int y0 = (int)floorf(y);
    int x0 = (int)floorf(x);
    bool cy = (y0 >= FH - 1);
    bool cx = (x0 >= FW - 1);
    int ylo = cy ? (FH - 1) : y0;
    int yhi = cy ? (FH - 1) : (y0 + 1);
    int xlo = cx ? (FW - 1) : x0;
    int xhi = cx ? (FW - 1) : (x0 + 1);
    float ly = cy ? 0.0f : (y - (float)y0);
    float lx = cx ? 0.0f : (x - (float)x0);
    float hy = 1.0f - ly;
    float hx = 1.0f - lx;
    float m  = valid ? 0.25f : 0.0f;   // fold valid-mask + mean(4 samples)

    *wout = make_float4(hy * hx * m, hy * lx * m, ly * hx * m, ly * lx * m);

    int bb = b * (FC * FHW);
    int p0 = ylo * FW + xlo;
    int p1 = ylo * FW + xhi;
    int p2 = yhi * FW + xlo;
    int p3 = yhi * FW + xhi;
    if (nhwc)
        *oout = make_int4(bb + p0 * FC, bb + p1 * FC, bb + p2 * FC, bb + p3 * FC);
    else
        *oout = make_int4(bb + p0, bb + p1, bb + p2, bb + p3);
}

__device__ __forceinline__ float fixnum(float v)
{
    return (v == v && v <= 3.402823466e38f && v >= -3.402823466e38f) ? v : 1e-8f;
}

// ---------------------------------------------------------------------------
// NCHW f32 -> NHWC fp16 transpose. Tile = 64 ch x 32 px, block 256.
// grid (FHW/32, FC/64, N). XOR-swizzled LDS: phase-1 b16 scatter hits all 32
// banks, phase-2 keeps 16B-aligned ds_read_b128. Read-once input -> nt loads.
// EMBEDDED MORTON SORT: block (0,0,0) additionally bitonic-sorts the RoI
// centers' Morton keys into perm[] AFTER its transpose tile. The sort (~5 us,
// 256 thr over 1024 LDS keys) rides under the 20 us BW-bound transpose grid,
// so the spatial ordering for the main kernel is FREE (round-4's standalone
// sort dispatch cost ~= its locality benefit; this keeps benefit, drops cost).
// ---------------------------------------------------------------------------
__global__ __launch_bounds__(256)
void transpose_f16_kernel(const float* __restrict__ in, __half* __restrict__ out,
                          const float* __restrict__ rois, int R,
                          int* __restrict__ perm)
{
    __shared__ __align__(16) __half tileT[32][72];   // stride 144 B
    __shared__ unsigned int skeys[1024];
    int b   = blockIdx.z;
    int p0  = blockIdx.x * 32;
    int c0  = blockIdx.y * 64;
    int tid = threadIdx.x;

    const float* inb  = in  + (size_t)b * FC * FHW;
    __half*      outb = out + (size_t)b * FHW * FC;

#pragma unroll
    for (int k = 0; k < 2; ++k) {
        int chl = k * 32 + (tid >> 3);       // 0..63 local channel
        int px4 = (tid & 7) * 4;             // 0,4,..,28 local pixel
        const nfloat4* src =
            (const nfloat4*)(inb + (size_t)(c0 + chl) * FHW + p0 + px4);
        nfloat4 v = __builtin_nontemporal_load(src);
        int g   = ((chl >> 3) ^ (px4 >> 2)) & 7;   // swizzled 8-ch group
        int col = (g << 3) | (chl & 7);
        tileT[px4 + 0][col] = __float2half(v.x);
        tileT[px4 + 1][col] = __float2half(v.y);
        tileT[px4 + 2][col] = __float2half(v.z);
        tileT[px4 + 3][col] = __float2half(v.w);
    }
    __syncthreads();

    int p = tid >> 3;                        // 0..31 pixel
    int q = tid & 7;                         // logical 8-ch group
    int g = (q ^ ((p >> 2) & 7));
    uint4 d = *(const uint4*)&tileT[p][g << 3];
    *(uint4*)(outb + (size_t)(p0 + p) * FC + c0 + q * 8) = d;

    // ---- designated block: Morton-sort RoI indices into perm --------------
    if (blockIdx.x == 0 && blockIdx.y == 0 && blockIdx.z == 0) {
        if (R > 1024) {                      // capacity guard: identity
            for (int i = tid; i < R; i += 256) perm[i] = i;
            return;
        }
        for (int i = tid; i < 1024; i += 256) {
            unsigned int key = 0xFFFFFFFFu;
            if (i < R) {
                float cx = rois[i * 6 + 1] * 0.25f;   // 0..200
                float cyf = rois[i * 6 + 2] * 0.25f;
                int qx = min(255, max(0, (int)(cx  * 1.28f)));
                int qy = min(255, max(0, (int)(cyf * 1.28f)));
                unsigned int m = 0;
#pragma unroll
                for (int k2 = 0; k2 < 8; ++k2)
                    m |= (((qx >> k2) & 1u) << (2 * k2)) |
                         (((qy >> k2) & 1u) << (2 * k2 + 1));
                key = (m << 12) | (unsigned int)i;    // idx in low 12 bits
            }
            skeys[i] = key;
        }
        __syncthreads();
#pragma unroll 1
        for (int k = 2; k <= 1024; k <<= 1) {
#pragma unroll 1
            for (int j = k >> 1; j > 0; j >>= 1) {
                // pairs (i, i^j) are disjoint within a pass -> race-free with
                // 256 threads x 4 slots; barrier between passes.
                for (int i = tid; i < 1024; i += 256) {
                    int ixj = i ^ j;
                    if (ixj > i) {
                        unsigned int a = skeys[i], bb2 = skeys[ixj];
                        bool up = ((i & k) == 0);
                        if ((a > bb2) == up) { skeys[i] = bb2; skeys[ixj] = a; }
                    }
                }
                __syncthreads();
            }
        }
        for (int i = tid; i < R; i += 256) perm[i] = (int)(skeys[i] & 0xFFFu);
    }
}

// ---------------------------------------------------------------------------
// Main kernel: 1D grid 4*R, block 512 thr = 64 channels of one RoI quarter.
// XCD QUARTER-PINNING: dispatch round-robins blocks over the 8 XCDs
// (xcd ~= bid % 8). Decode q=(bid>>1)&3, r=(bid>>3)*2+(bid&1)  (bijective on
// [0,4R) for even R) so channel-quarter q only ever runs on XCD pair
// {2q,2q+1}; each quarter touches a DISJOINT 10.24 MB slice of featT.
// SPATIAL ORDER: r is remapped through perm[] (Morton-sorted RoI centers) so
// temporally-adjacent blocks read nearby pixels -> live L2 set ~1.5 MB.
// 64 eight-lane groups; active group g (g < 49) owns exactly ONE bin. Lane
// owns 8 channels (16 B fp16 load per corner = one 128-B line per group ->
// line-perfect). All 16 corner loads issued back-to-back, then consumed with
// pure v_pk_fma_f16 broadcast-half2 weights. Output staged fp16 in LDS
// [bin][ch] (stride 66 halves), dumped with coalesced NONTEMPORAL float4
// stores (write-once 50 MB must not evict featT from L2/L3).
// ---------------------------------------------------------------------------
__global__ __launch_bounds__(512, 4)
void roi_nhwc_f16_kernel(const __half* __restrict__ feat,
                         const float* __restrict__ rois,
                         const int* __restrict__ perm,
                         float* __restrict__ out)
{
    __shared__ __align__(16) uint4 s_wh[NSAMP];  // 4 x broadcast-half2 weights
    __shared__ __align__(16) int4  s_o[NSAMP];
    __shared__ __half out_h[NBIN * OHS];

    int bid = blockIdx.x;
    int q   = (bid >> 1) & 3;            // quarter -> XCD pair {2q, 2q+1}
    int r   = (bid >> 3) * 2 + (bid & 1);
    int rs  = perm[r];                   // spatially-sorted RoI index
    int c0  = q * 64;                    // channel quarter
    int tid = threadIdx.x;

    const float* roi = rois + rs * 6;
    if (tid < NSAMP) {
        float4 w; int4 o;
        compute_sample(roi, tid, true, &w, &o);
        __half2 wh[4];
        wh[0] = __half2half2(__float2half(w.x));
        wh[1] = __half2half2(__float2half(w.y));
        wh[2] = __half2half2(__float2half(w.z));
        wh[3] = __half2half2(__float2half(w.w));
        s_wh[tid] = *(const uint4*)wh;
        s_o[tid]  = o;
    }
    __syncthreads();

    int grp   = tid >> 3;        // 0..63 eight-lane group = bin id
    int lane8 = tid & 7;
    int ch8   = lane8 * 8;       // local channel offset 0..56

    if (grp < NBIN) {
        const __half* fbase = feat + c0 + ch8;

        // ---- issue ALL 16 corner loads before consuming any ---------------
        uint4 la[16];
#pragma unroll
        for (int sub = 0; sub < 4; ++sub) {
            int4 o = s_o[grp * 4 + sub];
            la[sub * 4 + 0] = *(const uint4*)(fbase + o.x);
            la[sub * 4 + 1] = *(const uint4*)(fbase + o.y);
            la[sub * 4 + 2] = *(const uint4*)(fbase + o.z);
            la[sub * 4 + 3] = *(const uint4*)(fbase + o.w);
        }

        __half2 acc[4];
#pragma unroll
        for (int j = 0; j < 4; ++j) acc[j] = __half2half2(__float2half(0.0f));
#pragma unroll
        for (int sub = 0; sub < 4; ++sub) {
            uint4 whu = s_wh[grp * 4 + sub];
            const __half2* wh = (const __half2*)&whu;
#pragma unroll
            for (int c = 0; c < 4; ++c) {
                const __half2* h = (const __half2*)&la[sub * 4 + c];
#pragma unroll
                for (int j = 0; j < 4; ++j)
                    acc[j] = __hfma2(wh[c], h[j], acc[j]);
            }
        }
        __half2* dst = (__half2*)&out_h[grp * OHS + ch8];
#pragma unroll
        for (int j = 0; j < 4; ++j) dst[j] = acc[j];
    }
    __syncthreads();

    // Dump LDS [bin][ch_local] -> global [ch][bin], coalesced nt float4 stores.
    float* obase = out + (size_t)rs * (FC * NBIN) + (size_t)c0 * NBIN;
    for (int v4 = tid; v4 < (64 * NBIN) / 4; v4 += 512) {
        int f0 = v4 * 4;
        nfloat4 vals;
#pragma unroll
        for (int i = 0; i < 4; ++i) {
            int f = f0 + i;
            int c = f / NBIN;
            int b = f - c * NBIN;
            vals[i] = fixnum(__half2float(out_h[b * OHS + c]));
        }
        __builtin_nontemporal_store(vals, (nfloat4*)(obase + f0));
    }
}

// ---------------------------------------------------------------------------
// Fallback (ws too small / odd R): direct NCHW, correct but slow.
// ---------------------------------------------------------------------------
__global__ __launch_bounds__(256)
void roi_nchw_kernel(const float* __restrict__ feat,
                     const float* __restrict__ rois,
                     float* __restrict__ out)
{
    int r   = blockIdx.x;
    int tid = threadIdx.x;

    __shared__ float4 s_w[NSAMP];
    __shared__ int4   s_o[NSAMP];

    const float* roi = rois + r * 6;
    if (tid < NSAMP) {
        float4 w; int4 o;
        compute_sample(roi, tid, false, &w, &o);
        s_w[tid] = w;
        s_o[tid] = o;
    }
    __syncthreads();

    const float* fc = feat + (size_t)tid * FHW;
    float* obase = out + (size_t)r * (FC * NBIN) + (size_t)tid * NBIN;

    for (int bin = 0; bin < NBIN; ++bin) {
        float a = 0.0f;
#pragma unroll
        for (int k = 0; k < 4; ++k) {
            float4 w = s_w[bin * 4 + k];
            int4   o = s_o[bin * 4 + k];
            a += w.x * fc[o.x] + w.y * fc[o.y] + w.z * fc[o.z] + w.w * fc[o.w];
        }
        obase[bin] = fixnum(a);
    }
}

extern "C" void kernel_launch(void* const* d_in, const int* in_sizes, int n_in,
                              void* d_out, int out_size, void* d_ws, size_t ws_size,
                              hipStream_t stream)
{
    const float* feat = (const float*)d_in[0];
    const float* rois = (const float*)d_in[1];
    float* out = (float*)d_out;

    int R = in_sizes[1] / 6;
    int N = in_sizes[0] / (FC * FHW);
    size_t featT_halves = (size_t)N * FC * FHW;
    size_t need = featT_halves * sizeof(__half) + (size_t)R * sizeof(int);

    if (ws_size >= need && (R & 1) == 0) {
        __half* featT = (__half*)d_ws;
        int*    perm  = (int*)((char*)d_ws + featT_halves * sizeof(__half));
        dim3 tg(FHW / 32, FC / 64, N);
        transpose_f16_kernel<<<tg, 256, 0, stream>>>(feat, featT, rois, R, perm);
        roi_nhwc_f16_kernel<<<dim3(R * 4, 1, 1), 512, 0, stream>>>(featT, rois, perm, out);
    } else {
        roi_nchw_kernel<<<R, 256, 0, stream>>>(feat, rois, out);
    }
}

// Round 6
// 163.942 us; speedup vs baseline: 1.0494x; 1.0494x over previous
//
#include <hip/hip_runtime.h>
#include <hip/hip_fp16.h>

#define FH 200
#define FW 200
#define FHW 40000
#define FC 256
#define NBIN 49        // 7*7 output bins
#define NSAMP 196      // NBIN * 4 subsamples
#define OHS 66         // out_h [bin][ch] stride in halves = 33 dwords (odd ->
                       // full-period bank walk, <=2-way conflicts = free)

// Native clang vector for nontemporal builtins (HIP_vector_type is rejected).
typedef float  nfloat4 __attribute__((ext_vector_type(4)));

// ---------------------------------------------------------------------------
// Per-sample geometry: weights (pre-multiplied by valid-mask and 0.25 mean
// factor) and 4 bilinear-corner offsets (elements of the chosen layout).
// Matches the JAX reference (aligned coords, clamp-at-edge, valid in [-1,H]).
// __cosf/__sinf: hardware v_cos/v_sin, ~1e-5 rel err, irrelevant vs fp16 math.
// ---------------------------------------------------------------------------
__device__ __forceinline__ void compute_sample(const float* __restrict__ roi,
                                               int s, bool nhwc,
                                               float4* wout, int4* oout)
{
    int   b  = (int)roi[0];
    float cw = roi[1] * 0.25f - 0.5f;
    float ch = roi[2] * 0.25f - 0.5f;
    float rw = fmaxf(roi[3] * 0.25f, 1.0f);
    float rh = fmaxf(roi[4] * 0.25f, 1.0f);
    float th = roi[5] * 0.017453292519943295f;   // pi/180
    float ct = __cosf(th);
    float st = __sinf(th);
    float bin_h = rh / 7.0f;
    float bin_w = rw / 7.0f;

    int bin = s >> 2;
    int sub = s & 3;
    int iy  = sub >> 1;
    int ix  = sub & 1;
    int ph  = bin / 7;
    int pw  = bin - ph * 7;

    float fy = 0.25f + 0.5f * (float)iy;  // frac = {0.25, 0.75}
    float fx = 0.25f + 0.5f * (float)ix;
    float yy = -rh * 0.5f + ((float)ph + fy) * bin_h;
    float xx = -rw * 0.5f + ((float)pw + fx) * bin_w;
    float y  = yy * ct - xx * st + ch;
    float x  = yy * st + xx * ct + cw;

    bool valid = (y >= -1.0f) && (y <= (float)FH) && (x >= -1.0f) && (x <= (float)FW);
    y = fmaxf(y, 0.0f);
    x = fmaxf(x, 0.0f);
    int y0 = (int)floorf(y);
    int x0 = (int)floorf(x);
    bool cy = (y0 >= FH - 1);
    bool cx = (x0 >= FW - 1);
    int ylo = cy ? (FH - 1) : y0;
    int yhi = cy ? (FH - 1) : (y0 + 1);
    int xlo = cx ? (FW - 1) : x0;
    int xhi = cx ? (FW - 1) : (x0 + 1);
    float ly = cy ? 0.0f : (y - (float)y0);
    float lx = cx ? 0.0f : (x - (float)x0);
    float hy = 1.0f - ly;
    float hx = 1.0f - lx;
    float m  = valid ? 0.25f : 0.0f;   // fold valid-mask + mean(4 samples)

    *wout = make_float4(hy * hx * m, hy * lx * m, ly * hx * m, ly * lx * m);

    int bb = b * (FC * FHW);
    int p0 = ylo * FW + xlo;
    int p1 = ylo * FW + xhi;
    int p2 = yhi * FW + xlo;
    int p3 = yhi * FW + xhi;
    if (nhwc)
        *oout = make_int4(bb + p0 * FC, bb + p1 * FC, bb + p2 * FC, bb + p3 * FC);
    else
        *oout = make_int4(bb + p0, bb + p1, bb + p2, bb + p3);
}

__device__ __forceinline__ float fixnum(float v)
{
    return (v == v && v <= 3.402823466e38f && v >= -3.402823466e38f) ? v : 1e-8f;
}

// ---------------------------------------------------------------------------
// NCHW f32 -> NHWC fp16 transpose. Tile = 64 ch x 32 px, block 256.
// grid (FHW/32, FC/64, N). XOR-swizzled LDS: phase-1 b16 scatter hits all 32
// banks, phase-2 keeps 16B-aligned ds_read_b128.
// Input is read-once -> nontemporal loads (don't pollute L2/L3; featT, which
// the next kernel re-reads heavily, should keep the cache).
// NOTE (R5 post-mortem): do NOT embed the Morton sort here — the extra 4 KB
// LDS on every block cut transpose occupancy and block-0's sort tail sat on
// the inter-kernel critical path (+5.8 us net). Sorting in any form never
// beat its own cost on this workload.
// ---------------------------------------------------------------------------
__global__ __launch_bounds__(256)
void transpose_f16_kernel(const float* __restrict__ in, __half* __restrict__ out)
{
    __shared__ __align__(16) __half tileT[32][72];   // stride 144 B
    int b   = blockIdx.z;
    int p0  = blockIdx.x * 32;
    int c0  = blockIdx.y * 64;
    int tid = threadIdx.x;

    const float* inb  = in  + (size_t)b * FC * FHW;
    __half*      outb = out + (size_t)b * FHW * FC;

#pragma unroll
    for (int k = 0; k < 2; ++k) {
        int chl = k * 32 + (tid >> 3);       // 0..63 local channel
        int px4 = (tid & 7) * 4;             // 0,4,..,28 local pixel
        const nfloat4* src =
            (const nfloat4*)(inb + (size_t)(c0 + chl) * FHW + p0 + px4);
        nfloat4 v = __builtin_nontemporal_load(src);
        int g   = ((chl >> 3) ^ (px4 >> 2)) & 7;   // swizzled 8-ch group
        int col = (g << 3) | (chl & 7);
        tileT[px4 + 0][col] = __float2half(v.x);
        tileT[px4 + 1][col] = __float2half(v.y);
        tileT[px4 + 2][col] = __float2half(v.z);
        tileT[px4 + 3][col] = __float2half(v.w);
    }
    __syncthreads();

    int p = tid >> 3;                        // 0..31 pixel
    int q = tid & 7;                         // logical 8-ch group
    int g = (q ^ ((p >> 2) & 7));
    uint4 d = *(const uint4*)&tileT[p][g << 3];
    *(uint4*)(outb + (size_t)(p0 + p) * FC + c0 + q * 8) = d;
}

// ---------------------------------------------------------------------------
// Main kernel: 1D grid 4*R, block 512 thr = 64 channels of one RoI quarter.
// XCD QUARTER-PINNING: dispatch round-robins blocks over the 8 XCDs
// (xcd ~= bid % 8). Decode q=(bid>>1)&3, r=(bid>>3)*2+(bid&1)  (bijective on
// [0,4R) for even R) so channel-quarter q only ever runs on XCD pair
// {2q,2q+1}; each quarter touches a DISJOINT 10.24 MB slice of featT, so
// per-XCD working set drops 41 MB -> 10.24 MB -> L2 hit rate up (-6 us
// measured R3). Spatial RoI sorting on top of this never paid for itself
// (R4 standalone: cost ~= benefit; R5 embedded: regression).
// 64 eight-lane groups; active group g (g < 49) owns exactly ONE bin. Lane
// owns 8 channels (16 B fp16 load per corner = one 128-B line per group ->
// line-perfect). All 16 corner loads issued back-to-back, then consumed with
// pure v_pk_fma_f16 broadcast-half2 weights. Output staged fp16 in LDS
// [bin][ch] (stride 66 halves), dumped with coalesced NONTEMPORAL float4
// stores (write-once 50 MB must not evict featT from L2/L3).
// ---------------------------------------------------------------------------
__global__ __launch_bounds__(512, 4)
void roi_nhwc_f16_kernel(const __half* __restrict__ feat,
                         const float* __restrict__ rois,
                         float* __restrict__ out)
{
    __shared__ __align__(16) uint4 s_wh[NSAMP];  // 4 x broadcast-half2 weights
    __shared__ __align__(16) int4  s_o[NSAMP];
    __shared__ __half out_h[NBIN * OHS];

    int bid = blockIdx.x;
    int q   = (bid >> 1) & 3;            // quarter -> XCD pair {2q, 2q+1}
    int r   = (bid >> 3) * 2 + (bid & 1);
    int c0  = q * 64;                    // channel quarter
    int tid = threadIdx.x;

    const float* roi = rois + r * 6;
    if (tid < NSAMP) {
        float4 w; int4 o;
        compute_sample(roi, tid, true, &w, &o);
        __half2 wh[4];
        wh[0] = __half2half2(__float2half(w.x));
        wh[1] = __half2half2(__float2half(w.y));
        wh[2] = __half2half2(__float2half(w.z));
        wh[3] = __half2half2(__float2half(w.w));
        s_wh[tid] = *(const uint4*)wh;
        s_o[tid]  = o;
    }
    __syncthreads();

    int grp   = tid >> 3;        // 0..63 eight-lane group = bin id
    int lane8 = tid & 7;
    int ch8   = lane8 * 8;       // local channel offset 0..56

    if (grp < NBIN) {
        const __half* fbase = feat + c0 + ch8;

        // ---- issue ALL 16 corner loads before consuming any ---------------
        uint4 la[16];
#pragma unroll
        for (int sub = 0; sub < 4; ++sub) {
            int4 o = s_o[grp * 4 + sub];
            la[sub * 4 + 0] = *(const uint4*)(fbase + o.x);
            la[sub * 4 + 1] = *(const uint4*)(fbase + o.y);
            la[sub * 4 + 2] = *(const uint4*)(fbase + o.z);
            la[sub * 4 + 3] = *(const uint4*)(fbase + o.w);
        }

        __half2 acc[4];
#pragma unroll
        for (int j = 0; j < 4; ++j) acc[j] = __half2half2(__float2half(0.0f));
#pragma unroll
        for (int sub = 0; sub < 4; ++sub) {
            uint4 whu = s_wh[grp * 4 + sub];
            const __half2* wh = (const __half2*)&whu;
#pragma unroll
            for (int c = 0; c < 4; ++c) {
                const __half2* h = (const __half2*)&la[sub * 4 + c];
#pragma unroll
                for (int j = 0; j < 4; ++j)
                    acc[j] = __hfma2(wh[c], h[j], acc[j]);
            }
        }
        __half2* dst = (__half2*)&out_h[grp * OHS + ch8];
#pragma unroll
        for (int j = 0; j < 4; ++j) dst[j] = acc[j];
    }
    __syncthreads();

    // Dump LDS [bin][ch_local] -> global [ch][bin], coalesced nt float4 stores.
    float* obase = out + (size_t)r * (FC * NBIN) + (size_t)c0 * NBIN;
    for (int v4 = tid; v4 < (64 * NBIN) / 4; v4 += 512) {
        int f0 = v4 * 4;
        nfloat4 vals;
#pragma unroll
        for (int i = 0; i < 4; ++i) {
            int f = f0 + i;
            int c = f / NBIN;
            int b = f - c * NBIN;
            vals[i] = fixnum(__half2float(out_h[b * OHS + c]));
        }
        __builtin_nontemporal_store(vals, (nfloat4*)(obase + f0));
    }
}

// ---------------------------------------------------------------------------
// Fallback (ws too small / odd R): direct NCHW, correct but slow.
// ---------------------------------------------------------------------------
__global__ __launch_bounds__(256)
void roi_nchw_kernel(const float* __restrict__ feat,
                     const float* __restrict__ rois,
                     float* __restrict__ out)
{
    int r   = blockIdx.x;
    int tid = threadIdx.x;

    __shared__ float4 s_w[NSAMP];
    __shared__ int4   s_o[NSAMP];

    const float* roi = rois + r * 6;
    if (tid < NSAMP) {
        float4 w; int4 o;
        compute_sample(roi, tid, false, &w, &o);
        s_w[tid] = w;
        s_o[tid] = o;
    }
    __syncthreads();

    const float* fc = feat + (size_t)tid * FHW;
    float* obase = out + (size_t)r * (FC * NBIN) + (size_t)tid * NBIN;

    for (int bin = 0; bin < NBIN; ++bin) {
        float a = 0.0f;
#pragma unroll
        for (int k = 0; k < 4; ++k) {
            float4 w = s_w[bin * 4 + k];
            int4   o = s_o[bin * 4 + k];
            a += w.x * fc[o.x] + w.y * fc[o.y] + w.z * fc[o.z] + w.w * fc[o.w];
        }
        obase[bin] = fixnum(a);
    }
}

extern "C" void kernel_launch(void* const* d_in, const int* in_sizes, int n_in,
                              void* d_out, int out_size, void* d_ws, size_t ws_size,
                              hipStream_t stream)
{
    const float* feat = (const float*)d_in[0];
    const float* rois = (const float*)d_in[1];
    float* out = (float*)d_out;

    int R = in_sizes[1] / 6;
    int N = in_sizes[0] / (FC * FHW);
    size_t need = (size_t)in_sizes[0] * sizeof(__half);

    if (ws_size >= need && (R & 1) == 0) {
        __half* featT = (__half*)d_ws;
        dim3 tg(FHW / 32, FC / 64, N);
        transpose_f16_kernel<<<tg, 256, 0, stream>>>(feat, featT);
        roi_nhwc_f16_kernel<<<dim3(R * 4, 1, 1), 512, 0, stream>>>(featT, rois, out);
    } else {
        roi_nchw_kernel<<<R, 256, 0, stream>>>(feat, rois, out);
    }
}